// Round 15
// baseline (558.873 us; speedup 1.0000x reference)
//
#include <hip/hip_runtime.h>
#include <float.h>

#define N_PART 262144
#define GRID_DIM 256
#define NUM_CELLS (GRID_DIM * GRID_DIM)
#define KP 32                          // padded slots per cell (= reference K)
#define MAXNB 64

// ---------------- ws layout (all 256B-aligned) ----------------
// params : 3 uints (combined minx/miny/maxh bits; written by bin block 0)
// counts : NUM_CELLS+1 ints   (zeroed in D1; [NUM_CELLS] stays 0 = clip row)
// bMinX/Y/H : 1024 floats each (per-block reduce partials)
// Qraw   : (NUM_CELLS+1)*KP float4  ({x, y, id-bits, h}, arrival order)
//
// THREE dispatches. r15 change: rank_kernel DELETED -- the sorted-row
// requirement only exists to enumerate candidates in (cell-offset,
// ascending-id) order, and the query wave already holds all <=64 window
// candidates in lanes: the stable compaction rank is computed on the fly
// as  wrank = popc(valid & lanes<segbase) + #(same-seg valid with smaller
// id)  via a ~maxcnt __shfl loop over packed (id<<1)|valid. Segments are
// contiguous lane ranges, so cross-segment order is the ballot prefix.
// Query head: sequential pos2[w]/sup[w]; cell + S recomputed (r12-verified
// numerics); 9 uniform counts loads (256KB, L2-hot). Deletes rank's
// runtime (row sort + 4MB Qpad + 1MB random linR scatter + 4MB cinfo) and
// one dispatch gap. prep/bin byte-identical to r13/r14 (passed 2x).

__global__ __launch_bounds__(256) void prep_kernel(
        const float2* __restrict__ pos2, const float* __restrict__ sup,
        int* __restrict__ counts,
        float* __restrict__ bMinX, float* __restrict__ bMinY,
        float* __restrict__ bMaxH) {
    __shared__ unsigned s_minx, s_miny, s_maxh;
    int t = threadIdx.x, b = blockIdx.x;
    int tid = b * 256 + t;
    if (tid <= NUM_CELLS) counts[tid] = 0;
    if (t == 0) { s_minx = 0x7f7fffffu; s_miny = 0x7f7fffffu; s_maxh = 0u; }
    __syncthreads();
    float2 p = pos2[tid];
    float  h = sup[tid];
    // non-negative floats: uint compare == float compare
    atomicMin(&s_minx, __float_as_uint(p.x));
    atomicMin(&s_miny, __float_as_uint(p.y));
    atomicMax(&s_maxh, __float_as_uint(h));
    __syncthreads();
    if (t == 0) {
        bMinX[b] = __uint_as_float(s_minx);
        bMinY[b] = __uint_as_float(s_miny);
        bMaxH[b] = __uint_as_float(s_maxh);
    }
}

__global__ __launch_bounds__(256) void bin_kernel(
        const float2* __restrict__ pos2, const float* __restrict__ sup,
        const float* __restrict__ bMinX, const float* __restrict__ bMinY,
        const float* __restrict__ bMaxH,
        unsigned* __restrict__ params,
        int* __restrict__ counts, float4* __restrict__ Qraw) {
    __shared__ unsigned s_minx, s_miny, s_maxh;
    int t = threadIdx.x;
    int tid = blockIdx.x * 256 + t;
    // redundant per-block combine of 1024 partials: min/max exact and
    // order-independent -> identical result in every block
    if (t == 0) { s_minx = 0x7f7fffffu; s_miny = 0x7f7fffffu; s_maxh = 0u; }
    __syncthreads();
    {
        float mx = FLT_MAX, my = FLT_MAX, mh = 0.0f;
        for (int k = t; k < 1024; k += 256) {
            mx = fminf(mx, bMinX[k]);
            my = fminf(my, bMinY[k]);
            mh = fmaxf(mh, bMaxH[k]);
        }
        atomicMin(&s_minx, __float_as_uint(mx));
        atomicMin(&s_miny, __float_as_uint(my));
        atomicMax(&s_maxh, __float_as_uint(mh));
    }
    __syncthreads();
    if (blockIdx.x == 0 && t == 0) {    // publish combined params for query
        params[0] = s_minx; params[1] = s_miny; params[2] = s_maxh;
    }
    float hmax  = __uint_as_float(s_maxh);
    float qminx = __uint_as_float(s_minx) - hmax;
    float qminy = __uint_as_float(s_miny) - hmax;
    float2 p = pos2[tid];
    float  h = sup[tid];                // sequential load
    int cx = (int)ceilf((p.x - qminx) / hmax);
    int cy = (int)ceilf((p.y - qminy) / hmax);
    cx = min(max(cx, 0), GRID_DIM - 1);
    cy = min(max(cy, 0), GRID_DIM - 1);
    int c = cx + GRID_DIM * cy;
    int slot = atomicAdd(&counts[c], 1);
    if (slot < KP)                      // Poisson(4): never >32
        Qraw[(c << 5) + slot] = make_float4(p.x, p.y, __int_as_float(tid), h);
}

// One wave per PARTICLE in ID ORDER, reading UNSORTED Qraw rows; stable
// (cell-offset, ascending-id) candidate order is reconstructed in-wave.
// Head: pos2[w]/sup[w] sequential; cell c via params (ops identical to
// bin -> identical result); S = exact f32 threshold with
//   s2 <= S  <=>  RN(sqrt(s2)) <= h
// (mid = (h+nextafterf(h))/2; mid^2 exact in double, never a 24-bit f32 ->
// no ties; S = largest f32 <= mid^2; verified r2..r14). Non-temporal
// output stores (write-once rows). Junk lanes clamp to own row base
// (own cell cnt>=1 -> slot 0 written).
__global__ __launch_bounds__(256) void query_kernel(
        const float2* __restrict__ pos2, const float* __restrict__ sup,
        const unsigned* __restrict__ params,
        const int* __restrict__ counts, const float4* __restrict__ Qraw,
        float* __restrict__ outN, float* __restrict__ outC,
        float* __restrict__ outR) {
#pragma clang fp contract(off)
    __shared__ int   s_id[4][MAXNB];
    __shared__ float s_s2[4][MAXNB];

    int t    = threadIdx.x;
    int lane = t & 63;
    int wsl  = t >> 6;
    int bid  = blockIdx.x;
    int swz  = (bid & 7) * (int)(gridDim.x >> 3) + (bid >> 3);  // bijective XCD
    int w    = __builtin_amdgcn_readfirstlane(swz * 4 + wsl);   // particle id

    float2 pw = pos2[w];                 // sequential across waves
    float  hh = sup[w];
    float px = __int_as_float(__builtin_amdgcn_readfirstlane(__float_as_int(pw.x)));
    float py = __int_as_float(__builtin_amdgcn_readfirstlane(__float_as_int(pw.y)));
    float h  = __int_as_float(__builtin_amdgcn_readfirstlane(__float_as_int(hh)));

    // cell: identical ops to bin_kernel (same params -> identical result)
    float hmax  = __uint_as_float(params[2]);
    float qminx = __uint_as_float(params[0]) - hmax;
    float qminy = __uint_as_float(params[1]) - hmax;
    int cx = (int)ceilf((px - qminx) / hmax);
    int cy = (int)ceilf((py - qminy) / hmax);
    cx = min(max(cx, 0), GRID_DIM - 1);
    cy = min(max(cy, 0), GRID_DIM - 1);
    int c = __builtin_amdgcn_readfirstlane(cx + GRID_DIM * cy);

    // exact f32 threshold for RN(sqrt(s2)) <= h   (h > 0, normal)
    float  hn  = __int_as_float(__float_as_int(h) + 1);     // nextafter(h,inf)
    double mid = 0.5 * ((double)h + (double)hn);
    double t2  = mid * mid;                                  // exact (50 bits)
    float  S   = (float)t2;                                  // RN
    S = ((double)S > t2) ? __int_as_float(__float_as_int(S) - 1) : S;  // RD

    const int offs[9] = {-257, -1, 255, -256, 0, 256, -255, 1, 257};
    int cum[10], delta[9];
    cum[0] = 0;
    int maxc = 0;
#pragma unroll
    for (int o = 0; o < 9; o++) {
        int cl = min(max(c + offs[o], 0), NUM_CELLS);   // clip, dups at edges
        int cc = min(__builtin_amdgcn_readfirstlane(counts[cl]), KP);
        delta[o]   = (cl << 5) - cum[o];                // idx = ll + delta[o]
        cum[o + 1] = cum[o] + cc;
        maxc = max(maxc, cc);
    }
    int T = cum[9];

    if (T <= 64) {
        // ---- fast path: one candidate per lane; in-wave stable rank ----
        int dsel = delta[0], sb = 0, se = cum[1];
#pragma unroll
        for (int m = 1; m < 9; m++) {
            bool g = lane >= cum[m];
            dsel = g ? delta[m]   : dsel;
            sb   = g ? cum[m]     : sb;      // my segment's first lane
            se   = g ? cum[m + 1] : se;      // my segment's end lane
        }
        int segcnt = se - sb;
        int idx = (lane < T) ? (lane + dsel) : (c << 5);   // clamp junk lanes
        float4 q = Qraw[idx];
        float dx = q.x - px;
        float dy = q.y - py;
        float s2 = dx * dx + dy * dy;          // contract(off): match XLA
        bool valid = (s2 <= S) && (lane < T);  // junk/clamp lanes masked
        int myid = __float_as_int(q.z);
        int kv   = (myid << 1) | (valid ? 1 : 0);
        int rcomp = 0;                         // valid same-seg smaller-id
        for (int k = 0; k < maxc; k++) {       // maxc wave-uniform
            int kvk = __shfl(kv, sb + k);      // src always a real lane
            rcomp += ((k < segcnt) && (kvk & 1) && ((kvk >> 1) < myid)) ? 1 : 0;
        }
        unsigned long long bal = __ballot(valid);
        int before = (int)__popcll(bal & ((1ull << sb) - 1ull));  // sb<=63
        int wrank  = before + rcomp;           // < T <= 64 always
        if (valid) {
            s_id[wsl][wrank] = myid;
            s_s2[wsl][wrank] = s2;
        }
        int total = (int)__popcll(bal);
        // wave-private LDS, same-wave DS ops ordered: no barrier.
        int   jj = s_id[wsl][lane];
        float ss = s_s2[wsl][lane];
        bool inb = lane < total;
        float rh = __builtin_amdgcn_rsqf(S);   // ~1/h, 1ulp; tol-covered
        float vN = inb ? (float)jj : -1.0f;
        float vR = inb ? __builtin_amdgcn_sqrtf(ss) * rh : 0.0f;
        size_t base = (size_t)w * MAXNB;       // SEQUENTIAL across waves
        __builtin_nontemporal_store(vN, &outN[base + lane]);
        __builtin_nontemporal_store(vR, &outR[base + lane]);
        if (lane == 0)
            __builtin_nontemporal_store((float)total, &outC[w]);
    } else {
        // ---- rare path (P ~ 1e-6/cell): segments sequential, same rank ----
        int total = 0;
#pragma unroll 1
        for (int o = 0; o < 9; o++) {
            int sb = cum[o];
            int segcnt = cum[o + 1] - sb;      // wave-uniform
            if (segcnt == 0) continue;
            int rowb = delta[o] + sb;          // = cl << 5
            int kdx = (lane < segcnt) ? (rowb + lane) : rowb;
            float4 q = Qraw[kdx];
            float dx = q.x - px;
            float dy = q.y - py;
            float s2 = dx * dx + dy * dy;
            bool valid = (lane < segcnt) && (s2 <= S);
            int myid = __float_as_int(q.z);
            int kv   = (myid << 1) | (valid ? 1 : 0);
            int rcomp = 0;
            for (int k = 0; k < segcnt; k++) {
                int kvk = __shfl(kv, k);
                rcomp += ((kvk & 1) && ((kvk >> 1) < myid)) ? 1 : 0;
            }
            int wrank = total + rcomp;
            if (valid && wrank < MAXNB) {
                s_id[wsl][wrank] = myid;
                s_s2[wsl][wrank] = s2;
            }
            total += (int)__popcll(__ballot(valid));
        }
        int stored = min(total, MAXNB);
        int   jj = s_id[wsl][lane];
        float ss = s_s2[wsl][lane];
        bool inb = lane < stored;
        float rh = __builtin_amdgcn_rsqf(S);
        float vN = inb ? (float)jj : -1.0f;
        float vR = inb ? __builtin_amdgcn_sqrtf(ss) * rh : 0.0f;
        size_t base = (size_t)w * MAXNB;
        __builtin_nontemporal_store(vN, &outN[base + lane]);
        __builtin_nontemporal_store(vR, &outR[base + lane]);
        if (lane == 0)
            __builtin_nontemporal_store((float)total, &outC[w]);
    }
}

extern "C" void kernel_launch(void* const* d_in, const int* in_sizes, int n_in,
                              void* d_out, int out_size, void* d_ws, size_t ws_size,
                              hipStream_t stream) {
    const float2* pos2 = (const float2*)d_in[0];
    const float*  sup  = (const float*)d_in[1];

    char* p = (char*)d_ws;
    auto alloc = [&](size_t bytes) {
        char* q = p;
        p += (bytes + 255) & ~(size_t)255;
        return q;
    };
    unsigned* params = (unsigned*)alloc(256);
    int*    counts = (int*)alloc((size_t)(NUM_CELLS + 1) * 4);
    float*  bMinX  = (float*)alloc(1024 * 4);
    float*  bMinY  = (float*)alloc(1024 * 4);
    float*  bMaxH  = (float*)alloc(1024 * 4);
    float4* Qraw   = (float4*)alloc((size_t)(NUM_CELLS + 1) * KP * 16);

    float* out  = (float*)d_out;
    float* outN = out;                              // N*64 neighbor ids (as f32)
    float* outC = out + (size_t)N_PART * MAXNB;     // N counts
    float* outR = outC + N_PART;                    // N*64 radial

    prep_kernel<<<N_PART / 256, 256, 0, stream>>>(pos2, sup, counts,
                                                  bMinX, bMinY, bMaxH);
    bin_kernel<<<N_PART / 256, 256, 0, stream>>>(pos2, sup, bMinX, bMinY,
                                                 bMaxH, params, counts, Qraw);
    // one wave per particle, ID ORDER: N_PART waves = N_PART/4 blocks
    query_kernel<<<N_PART / 4, 256, 0, stream>>>(pos2, sup, params, counts,
                                                 Qraw, outN, outC, outR);
}

// Round 16
// 276.239 us; speedup vs baseline: 2.0231x; 2.0231x over previous
//
#include <hip/hip_runtime.h>
#include <float.h>

#define N_PART 262144
#define GRID_DIM 256
#define NUM_CELLS (GRID_DIM * GRID_DIM)
#define KP 32                          // padded slots per cell (= reference K)
#define MAXNB 64

// ---------------- ws layout (all 256B-aligned) ----------------
// params : 3 uints (combined minx/miny/maxh bits; written by bin block 0)
// counts : NUM_CELLS+1 ints   (zeroed in D1; [NUM_CELLS] stays 0 = clip row)
// bMinX/Y/H : 1024 floats each (per-block reduce partials)
// Qraw   : (NUM_CELLS+1)*KP float4  ({x, y, id-bits, h}, arrival order)
// Qpad   : (NUM_CELLS+1)*KP + 64 float4  (same records, id-sorted per row)
//
// r15 post-mortem: in-wave rank via variable-lane __shfl = serialized
// ds_bpermute chains -> 431us VALU-bound. FALSIFIED. But r15 proved the
// fetch story: with a lean gather set, query FETCH = 90MB (vs 232 for the
// 14MB hot-set r13 layout) -- id-order fetch is an L2-CAPACITY effect.
// r16 = r13's fast query body (sorted Qpad + ballot-prefix compaction)
// + r15's memory diet: gather set is Qpad 4MB + counts 0.26MB only.
//   - own px,py,S from SEQUENTIAL pos2[w]/sup[w] (r12-verified recompute)
//   - cum/delta from 9 uniform counts loads (r6-r9-verified pattern)
//   - rank_kernel loses linR scatter + cinfo + all f64 math
//   - NT output stores kept (r14: -24MB fetch, free)

__global__ __launch_bounds__(256) void prep_kernel(
        const float2* __restrict__ pos2, const float* __restrict__ sup,
        int* __restrict__ counts,
        float* __restrict__ bMinX, float* __restrict__ bMinY,
        float* __restrict__ bMaxH) {
    __shared__ unsigned s_minx, s_miny, s_maxh;
    int t = threadIdx.x, b = blockIdx.x;
    int tid = b * 256 + t;
    if (tid <= NUM_CELLS) counts[tid] = 0;
    if (t == 0) { s_minx = 0x7f7fffffu; s_miny = 0x7f7fffffu; s_maxh = 0u; }
    __syncthreads();
    float2 p = pos2[tid];
    float  h = sup[tid];
    // non-negative floats: uint compare == float compare
    atomicMin(&s_minx, __float_as_uint(p.x));
    atomicMin(&s_miny, __float_as_uint(p.y));
    atomicMax(&s_maxh, __float_as_uint(h));
    __syncthreads();
    if (t == 0) {
        bMinX[b] = __uint_as_float(s_minx);
        bMinY[b] = __uint_as_float(s_miny);
        bMaxH[b] = __uint_as_float(s_maxh);
    }
}

__global__ __launch_bounds__(256) void bin_kernel(
        const float2* __restrict__ pos2, const float* __restrict__ sup,
        const float* __restrict__ bMinX, const float* __restrict__ bMinY,
        const float* __restrict__ bMaxH,
        unsigned* __restrict__ params,
        int* __restrict__ counts, float4* __restrict__ Qraw) {
    __shared__ unsigned s_minx, s_miny, s_maxh;
    int t = threadIdx.x;
    int tid = blockIdx.x * 256 + t;
    // redundant per-block combine of 1024 partials: min/max exact and
    // order-independent -> identical result in every block
    if (t == 0) { s_minx = 0x7f7fffffu; s_miny = 0x7f7fffffu; s_maxh = 0u; }
    __syncthreads();
    {
        float mx = FLT_MAX, my = FLT_MAX, mh = 0.0f;
        for (int k = t; k < 1024; k += 256) {
            mx = fminf(mx, bMinX[k]);
            my = fminf(my, bMinY[k]);
            mh = fmaxf(mh, bMaxH[k]);
        }
        atomicMin(&s_minx, __float_as_uint(mx));
        atomicMin(&s_miny, __float_as_uint(my));
        atomicMax(&s_maxh, __float_as_uint(mh));
    }
    __syncthreads();
    if (blockIdx.x == 0 && t == 0) {    // publish combined params for query
        params[0] = s_minx; params[1] = s_miny; params[2] = s_maxh;
    }
    float hmax  = __uint_as_float(s_maxh);
    float qminx = __uint_as_float(s_minx) - hmax;
    float qminy = __uint_as_float(s_miny) - hmax;
    float2 p = pos2[tid];
    float  h = sup[tid];                // sequential load
    int cx = (int)ceilf((p.x - qminx) / hmax);
    int cy = (int)ceilf((p.y - qminy) / hmax);
    cx = min(max(cx, 0), GRID_DIM - 1);
    cy = min(max(cy, 0), GRID_DIM - 1);
    int c = cx + GRID_DIM * cy;
    int slot = atomicAdd(&counts[c], 1);
    if (slot < KP)                      // Poisson(4): never >32
        Qraw[(c << 5) + slot] = make_float4(p.x, p.y, __int_as_float(tid), h);
}

// ROW-LOCAL ordered emit (r13-verified core, slimmed): thread (c,s) handles
// arrival slots s, s+8, ... All reads are the cell's own Qraw row (L1-hot,
// coalesced across the 8 sibling threads). rank = #(smaller ids in row)
// puts each record at its id-sorted position (stable argsort semantics).
// No linR, no cinfo, no f64: the record is copied as-is to its sorted slot.
__global__ __launch_bounds__(256) void rank_kernel(
        const int* __restrict__ counts, const float4* __restrict__ Qraw,
        float4* __restrict__ Qpad) {
    int tid = blockIdx.x * 256 + threadIdx.x;   // NUM_CELLS*8 threads
    int c   = tid >> 3;
    int s0  = tid & 7;
    int cnt = min(counts[c], KP);
    const float4* row = Qraw + (c << 5);
    for (int sl = s0; sl < cnt; sl += 8) {
        float4 rec = row[sl];
        int id = __float_as_int(rec.z);
        int rank = 0;
        for (int k = 0; k < cnt; k++)
            rank += (__float_as_int(row[k].z) < id);
        Qpad[(c << 5) + rank] = rec;    // bitwise copy: numerics identical
    }
}

// One wave per PARTICLE in ID ORDER (r13-verified body + lean head).
// Head: pos2[w]/sup[w] SEQUENTIAL; cell via params (ops identical to bin ->
// identical result; r12-verified); S = exact f32 threshold with
//   s2 <= S  <=>  RN(sqrt(s2)) <= h
// (mid = (h+nextafterf(h))/2; mid^2 exact in double, never a 24-bit f32 ->
// no ties; S = largest f32 <= mid^2; verified r2..r14); cum/delta from 9
// uniform counts loads (L2-hot 256KB). Gather set = Qpad + counts only
// (~4.3MB: near the 4MB per-XCD L2). Window gather, masked-ballot stable
// compaction, LDS bounce, NT sequential 256B row stores. Junk lanes clamp
// to (c<<5): own cell cnt>=1 -> slot 0 written.
__global__ __launch_bounds__(256) void query_kernel(
        const float2* __restrict__ pos2, const float* __restrict__ sup,
        const unsigned* __restrict__ params,
        const int* __restrict__ counts, const float4* __restrict__ Qpad,
        float* __restrict__ outN, float* __restrict__ outC,
        float* __restrict__ outR) {
#pragma clang fp contract(off)
    __shared__ int   s_id[4][MAXNB];
    __shared__ float s_s2[4][MAXNB];

    int t    = threadIdx.x;
    int lane = t & 63;
    int wsl  = t >> 6;
    int bid  = blockIdx.x;
    int swz  = (bid & 7) * (int)(gridDim.x >> 3) + (bid >> 3);  // bijective XCD
    int w    = __builtin_amdgcn_readfirstlane(swz * 4 + wsl);   // particle id

    float2 pw = pos2[w];                 // sequential across waves
    float  hh = sup[w];
    float px = __int_as_float(__builtin_amdgcn_readfirstlane(__float_as_int(pw.x)));
    float py = __int_as_float(__builtin_amdgcn_readfirstlane(__float_as_int(pw.y)));
    float h  = __int_as_float(__builtin_amdgcn_readfirstlane(__float_as_int(hh)));

    // cell: identical ops to bin_kernel (same params -> identical result)
    float hmax  = __uint_as_float(params[2]);
    float qminx = __uint_as_float(params[0]) - hmax;
    float qminy = __uint_as_float(params[1]) - hmax;
    int cx = (int)ceilf((px - qminx) / hmax);
    int cy = (int)ceilf((py - qminy) / hmax);
    cx = min(max(cx, 0), GRID_DIM - 1);
    cy = min(max(cy, 0), GRID_DIM - 1);
    int c = __builtin_amdgcn_readfirstlane(cx + GRID_DIM * cy);

    // exact f32 threshold for RN(sqrt(s2)) <= h   (h > 0, normal)
    float  hn  = __int_as_float(__float_as_int(h) + 1);     // nextafter(h,inf)
    double mid = 0.5 * ((double)h + (double)hn);
    double t2  = mid * mid;                                  // exact (50 bits)
    float  S   = (float)t2;                                  // RN
    S = ((double)S > t2) ? __int_as_float(__float_as_int(S) - 1) : S;  // RD

    const int offs[9] = {-257, -1, 255, -256, 0, 256, -255, 1, 257};
    int cum[10], delta[9];
    cum[0] = 0;
#pragma unroll
    for (int o = 0; o < 9; o++) {
        int cl = min(max(c + offs[o], 0), NUM_CELLS);   // clip, dups at edges
        int cc = min(__builtin_amdgcn_readfirstlane(counts[cl]), KP);
        delta[o]   = (cl << 5) - cum[o];                // idx = ll + delta[o]
        cum[o + 1] = cum[o] + cc;
    }
    int T = cum[9];

    if (T <= 64) {
        // ---- fast path: one candidate per lane, ballot-prefix rank ----
        int dsel = delta[0];
#pragma unroll
        for (int m = 1; m < 9; m++)
            dsel = (lane >= cum[m]) ? delta[m] : dsel;
        int idx = (lane < T) ? (lane + dsel) : (c << 5);   // clamp junk lanes
        float4 q = Qpad[idx];                              //  to a hot line
        unsigned long long maskT = (T >= 64) ? ~0ull : ((1ull << T) - 1ull);
        float dx = q.x - px;
        float dy = q.y - py;
        float s2 = dx * dx + dy * dy;          // contract(off): match XLA
        bool keep = (s2 <= S) && (lane < T);   // junk/clamp lanes masked
        unsigned long long bal = __ballot(s2 <= S) & maskT;
        int rank = __builtin_amdgcn_mbcnt_hi(
            (unsigned)(bal >> 32),
            __builtin_amdgcn_mbcnt_lo((unsigned)bal, 0));
        if (keep) {                            // T<=64 -> rank < 64 always
            s_id[wsl][rank] = __float_as_int(q.z);
            s_s2[wsl][rank] = s2;
        }
        int total = (int)__popcll(bal);
        // wave-private LDS, same-wave DS ops ordered: no barrier. Stale
        // entries beyond 'total' discarded by the inb select.
        int   jj = s_id[wsl][lane];
        float ss = s_s2[wsl][lane];
        bool inb = lane < total;
        float rh = __builtin_amdgcn_rsqf(S);   // ~1/h, 1ulp; tol-covered
        float vN = inb ? (float)jj : -1.0f;
        float vR = inb ? __builtin_amdgcn_sqrtf(ss) * rh : 0.0f;
        size_t base = (size_t)w * MAXNB;       // SEQUENTIAL across waves
        __builtin_nontemporal_store(vN, &outN[base + lane]);
        __builtin_nontemporal_store(vR, &outR[base + lane]);
        if (lane == 0)
            __builtin_nontemporal_store((float)total, &outC[w]);
    } else {
        // ---- rare path (P(T>64) ~ 1e-5 per cell): batched, re-loads ----
        int total = 0;
        for (int b0 = 0; b0 < T; b0 += 64) {
            int ll = b0 + lane;
            int dsel = delta[0];
#pragma unroll
            for (int m = 1; m < 9; m++)
                dsel = (ll >= cum[m]) ? delta[m] : dsel;
            float4 q = Qpad[ll + dsel];        // in-bounds: slot<32, cl<=NC
            float dx = q.x - px;
            float dy = q.y - py;
            float s2 = dx * dx + dy * dy;
            int rem = T - b0;
            unsigned long long maskT =
                (rem >= 64) ? ~0ull : ((1ull << rem) - 1ull);
            unsigned long long bal = __ballot(s2 <= S) & maskT;
            int rank = __builtin_amdgcn_mbcnt_hi(
                (unsigned)(bal >> 32),
                __builtin_amdgcn_mbcnt_lo((unsigned)bal, 0));
            int ww = total + rank;
            if ((s2 <= S) && (ll < T) && (ww < MAXNB)) {
                s_id[wsl][ww] = __float_as_int(q.z);
                s_s2[wsl][ww] = s2;
            }
            total += (int)__popcll(bal);
        }
        int stored = min(total, MAXNB);
        int   jj = s_id[wsl][lane];
        float ss = s_s2[wsl][lane];
        bool inb = lane < stored;
        float rh = __builtin_amdgcn_rsqf(S);
        float vN = inb ? (float)jj : -1.0f;
        float vR = inb ? __builtin_amdgcn_sqrtf(ss) * rh : 0.0f;
        size_t base = (size_t)w * MAXNB;
        __builtin_nontemporal_store(vN, &outN[base + lane]);
        __builtin_nontemporal_store(vR, &outR[base + lane]);
        if (lane == 0)
            __builtin_nontemporal_store((float)total, &outC[w]);
    }
}

extern "C" void kernel_launch(void* const* d_in, const int* in_sizes, int n_in,
                              void* d_out, int out_size, void* d_ws, size_t ws_size,
                              hipStream_t stream) {
    const float2* pos2 = (const float2*)d_in[0];
    const float*  sup  = (const float*)d_in[1];

    char* p = (char*)d_ws;
    auto alloc = [&](size_t bytes) {
        char* q = p;
        p += (bytes + 255) & ~(size_t)255;
        return q;
    };
    unsigned* params = (unsigned*)alloc(256);
    int*    counts = (int*)alloc((size_t)(NUM_CELLS + 1) * 4);
    float*  bMinX  = (float*)alloc(1024 * 4);
    float*  bMinY  = (float*)alloc(1024 * 4);
    float*  bMaxH  = (float*)alloc(1024 * 4);
    float4* Qraw   = (float4*)alloc((size_t)(NUM_CELLS + 1) * KP * 16);
    float4* Qpad   = (float4*)alloc(((size_t)(NUM_CELLS + 1) * KP + 64) * 16);

    float* out  = (float*)d_out;
    float* outN = out;                              // N*64 neighbor ids (as f32)
    float* outC = out + (size_t)N_PART * MAXNB;     // N counts
    float* outR = outC + N_PART;                    // N*64 radial

    prep_kernel<<<N_PART / 256, 256, 0, stream>>>(pos2, sup, counts,
                                                  bMinX, bMinY, bMaxH);
    bin_kernel<<<N_PART / 256, 256, 0, stream>>>(pos2, sup, bMinX, bMinY,
                                                 bMaxH, params, counts, Qraw);
    // thread per (cell, slot-class): NUM_CELLS*8 threads
    rank_kernel<<<NUM_CELLS * 8 / 256, 256, 0, stream>>>(counts, Qraw, Qpad);
    // one wave per particle, ID ORDER: N_PART waves = N_PART/4 blocks
    query_kernel<<<N_PART / 4, 256, 0, stream>>>(pos2, sup, params, counts,
                                                 Qpad, outN, outC, outR);
}

// Round 17
// 265.871 us; speedup vs baseline: 2.1020x; 1.0390x over previous
//
#include <hip/hip_runtime.h>
#include <float.h>

#define N_PART 262144
#define GRID_DIM 256
#define NUM_CELLS (GRID_DIM * GRID_DIM)
#define KP 32                          // padded slots per cell (= reference K)
#define MAXNB 64

// ---------------- ws layout (all 256B-aligned) ----------------
// params : 3 uints (combined minx/miny/maxh bits; written by bin block 0)
// counts : NUM_CELLS+1 ints   (zeroed in D1; [NUM_CELLS] stays 0 = clip row)
// bMinX/Y/H : 1024 floats each (per-block reduce partials)
// Qraw   : (NUM_CELLS+1)*KP float4  ({x, y, id-bits, h}, arrival order)
// Qpad   : (NUM_CELLS+1)*KP + 64 float4  ({x, y, id-bits, S}, id-sorted)
// linR   : N ints              ((cell<<5)|rank per particle id)
// cinfo  : NUM_CELLS * 4 int4  (9-cell prefix sums, 64B/cell = 1 line/wave)
//
// FINAL REVERT to the session's best-passed kernel (r13, 264.4us).
// Established walls (17 rounds):
//  - query: id-order = minimal-unique-line fetch (~186-232MB) + sequential
//    writes -> ~102us at ~3.6TB/s; cell-order = minimal fetch but random
//    256B writes at 1.4TB/s -> ~100us. Output addr is id-fixed, gather
//    locality cell-fixed -> no ordering gets both (r6/r8/r10/r12/r15/r16).
//  - build: ~162us fixed dispatch cost across 5 compositions; cooperative
//    fusion costs the same per sync (r3/r5); 3-dispatch needs in-wave
//    sort (+330us VALU, r15).

__global__ __launch_bounds__(256) void prep_kernel(
        const float2* __restrict__ pos2, const float* __restrict__ sup,
        int* __restrict__ counts,
        float* __restrict__ bMinX, float* __restrict__ bMinY,
        float* __restrict__ bMaxH) {
    __shared__ unsigned s_minx, s_miny, s_maxh;
    int t = threadIdx.x, b = blockIdx.x;
    int tid = b * 256 + t;
    if (tid <= NUM_CELLS) counts[tid] = 0;
    if (t == 0) { s_minx = 0x7f7fffffu; s_miny = 0x7f7fffffu; s_maxh = 0u; }
    __syncthreads();
    float2 p = pos2[tid];
    float  h = sup[tid];
    // non-negative floats: uint compare == float compare
    atomicMin(&s_minx, __float_as_uint(p.x));
    atomicMin(&s_miny, __float_as_uint(p.y));
    atomicMax(&s_maxh, __float_as_uint(h));
    __syncthreads();
    if (t == 0) {
        bMinX[b] = __uint_as_float(s_minx);
        bMinY[b] = __uint_as_float(s_miny);
        bMaxH[b] = __uint_as_float(s_maxh);
    }
}

__global__ __launch_bounds__(256) void bin_kernel(
        const float2* __restrict__ pos2, const float* __restrict__ sup,
        const float* __restrict__ bMinX, const float* __restrict__ bMinY,
        const float* __restrict__ bMaxH,
        unsigned* __restrict__ params,
        int* __restrict__ counts, float4* __restrict__ Qraw) {
    __shared__ unsigned s_minx, s_miny, s_maxh;
    int t = threadIdx.x;
    int tid = blockIdx.x * 256 + t;
    // redundant per-block combine of 1024 partials: min/max exact and
    // order-independent -> identical result in every block
    if (t == 0) { s_minx = 0x7f7fffffu; s_miny = 0x7f7fffffu; s_maxh = 0u; }
    __syncthreads();
    {
        float mx = FLT_MAX, my = FLT_MAX, mh = 0.0f;
        for (int k = t; k < 1024; k += 256) {
            mx = fminf(mx, bMinX[k]);
            my = fminf(my, bMinY[k]);
            mh = fmaxf(mh, bMaxH[k]);
        }
        atomicMin(&s_minx, __float_as_uint(mx));
        atomicMin(&s_miny, __float_as_uint(my));
        atomicMax(&s_maxh, __float_as_uint(mh));
    }
    __syncthreads();
    if (blockIdx.x == 0 && t == 0) {    // publish combined params (debug)
        params[0] = s_minx; params[1] = s_miny; params[2] = s_maxh;
    }
    float hmax  = __uint_as_float(s_maxh);
    float qminx = __uint_as_float(s_minx) - hmax;
    float qminy = __uint_as_float(s_miny) - hmax;
    float2 p = pos2[tid];
    float  h = sup[tid];                // sequential load
    int cx = (int)ceilf((p.x - qminx) / hmax);
    int cy = (int)ceilf((p.y - qminy) / hmax);
    cx = min(max(cx, 0), GRID_DIM - 1);
    cy = min(max(cy, 0), GRID_DIM - 1);
    int c = cx + GRID_DIM * cy;
    int slot = atomicAdd(&counts[c], 1);
    if (slot < KP)                      // Poisson(4): never >32
        Qraw[(c << 5) + slot] = make_float4(p.x, p.y, __int_as_float(tid), h);
}

// ROW-LOCAL ordered emit: thread (c,s) handles arrival slots s, s+8, ...
// All reads are the cell's own Qraw row (L1-hot, coalesced across the 8
// sibling threads); NO random gathers (pos/h travel inside the record).
// rank = #(smaller ids in row) puts each record at its id-sorted position
// (stable argsort semantics). S = exact f32 threshold:
//   s2 <= S  <=>  RN(sqrt(s2)) <= h
// mid = (h + nextafterf(h))/2; mid^2 exact in double (50 bits), never a
// 24-bit f32 -> no ties; S = largest f32 <= mid^2. (verified since r2)
__global__ __launch_bounds__(256) void rank_kernel(
        const int* __restrict__ counts, const float4* __restrict__ Qraw,
        float4* __restrict__ Qpad, int* __restrict__ linR,
        int4* __restrict__ cinfo) {
    int tid = blockIdx.x * 256 + threadIdx.x;   // NUM_CELLS*8 threads
    int c   = tid >> 3;
    int s0  = tid & 7;
    int cnt = min(counts[c], KP);
    const float4* row = Qraw + (c << 5);
    for (int sl = s0; sl < cnt; sl += 8) {
        float4 rec = row[sl];
        int id = __float_as_int(rec.z);
        int rank = 0;
        for (int k = 0; k < cnt; k++)
            rank += (__float_as_int(row[k].z) < id);
        float h = rec.w;
        float  hn  = __int_as_float(__float_as_int(h) + 1); // nextafter(h,inf)
        double mid = 0.5 * ((double)h + (double)hn);
        double t2  = mid * mid;                              // exact
        float  S   = (float)t2;                              // RN
        S = ((double)S > t2) ? __int_as_float(__float_as_int(S) - 1) : S;
        Qpad[(c << 5) + rank] = make_float4(rec.x, rec.y, rec.z, S);
        linR[id] = (c << 5) | rank;     // rank < 32: fits 5 bits
    }
    if (s0 == 0) {                      // one thread per cell: prefix sums
        const int offs[9] = {-257, -1, 255, -256, 0, 256, -255, 1, 257};
        int cum = 0;
        int v[9];
#pragma unroll
        for (int o = 0; o < 9; o++) {
            int cl = min(max(c + offs[o], 0), NUM_CELLS);   // clip, dups incl.
            cum += min(counts[cl], KP);
            v[o] = cum;
        }
        cinfo[(c << 2) + 0] = make_int4(v[0], v[1], v[2], v[3]);
        cinfo[(c << 2) + 1] = make_int4(v[4], v[5], v[6], v[7]);
        cinfo[(c << 2) + 2] = make_int4(v[8], 0, 0, 0);
    }
}

// One wave per PARTICLE in ID ORDER (r10/r13-verified body): linR ->
// own record (px,py,S) -> one 64B cinfo line -> register window gather ->
// masked-ballot stable compaction -> LDS bounce -> sequential 256B row
// stores. Junk lanes (>=T) clamp to the own-record line (always written).
__global__ __launch_bounds__(256) void query_kernel(
        const int* __restrict__ linR, const int4* __restrict__ cinfo,
        const float4* __restrict__ Qpad,
        float* __restrict__ outN, float* __restrict__ outC,
        float* __restrict__ outR) {
#pragma clang fp contract(off)
    __shared__ int   s_id[4][MAXNB];
    __shared__ float s_s2[4][MAXNB];

    int t    = threadIdx.x;
    int lane = t & 63;
    int wsl  = t >> 6;
    int bid  = blockIdx.x;
    int swz  = (bid & 7) * (int)(gridDim.x >> 3) + (bid >> 3);  // bijective XCD
    int w    = __builtin_amdgcn_readfirstlane(swz * 4 + wsl);   // particle id

    int lr = __builtin_amdgcn_readfirstlane(linR[w]);
    int c  = lr >> 5;

    int4 ca = cinfo[(c << 2) + 0];      // one 64B line, uniform
    int4 cb = cinfo[(c << 2) + 1];
    int4 cz = cinfo[(c << 2) + 2];
    float4 me = Qpad[lr];               // own record: {x, y, id-bits, S}
    float px = me.x, py = me.y, S = me.w;

    const int offs[9] = {-257, -1, 255, -256, 0, 256, -255, 1, 257};
    int cum[10] = {0, ca.x, ca.y, ca.z, ca.w, cb.x, cb.y, cb.z, cb.w, };
    cum[9] = cz.x;
    int T = cum[9];
    int delta[9];
#pragma unroll
    for (int o = 0; o < 9; o++) {
        int cl = min(max(c + offs[o], 0), NUM_CELLS);   // clip, dups at edges
        delta[o] = (cl << 5) - cum[o];                  // idx = ll + delta[o]
    }

    if (T <= 64) {
        // ---- fast path: one candidate per lane ----
        int dsel = delta[0];
#pragma unroll
        for (int m = 1; m < 9; m++)
            dsel = (lane >= cum[m]) ? delta[m] : dsel;
        int idx = (lane < T) ? (lane + dsel) : lr;      // clamp junk lanes to
        float4 q = Qpad[idx];                           //  the hot own-line
        unsigned long long maskT = (T >= 64) ? ~0ull : ((1ull << T) - 1ull);
        float dx = q.x - px;
        float dy = q.y - py;
        float s2 = dx * dx + dy * dy;          // contract(off): match XLA
        bool keep = (s2 <= S) && (lane < T);   // junk/clamp lanes masked
        unsigned long long bal = __ballot(s2 <= S) & maskT;
        int rank = __builtin_amdgcn_mbcnt_hi(
            (unsigned)(bal >> 32),
            __builtin_amdgcn_mbcnt_lo((unsigned)bal, 0));
        if (keep) {                            // T<=64 -> rank < 64 always
            s_id[wsl][rank] = __float_as_int(q.z);
            s_s2[wsl][rank] = s2;
        }
        int total = (int)__popcll(bal);
        // wave-private LDS, same-wave DS ops ordered: no barrier. Stale
        // entries beyond 'total' discarded by the inb select.
        int   jj = s_id[wsl][lane];
        float ss = s_s2[wsl][lane];
        bool inb = lane < total;
        float rh = __builtin_amdgcn_rsqf(S);   // ~1/h, 1ulp; tol-covered
        float vN = inb ? (float)jj : -1.0f;
        float vR = inb ? __builtin_amdgcn_sqrtf(ss) * rh : 0.0f;
        size_t base = (size_t)w * MAXNB;       // SEQUENTIAL across waves
        outN[base + lane] = vN;
        outR[base + lane] = vR;
        if (lane == 0) outC[w] = (float)total;
    } else {
        // ---- rare path (P(T>64) ~ 1e-5 per cell): batched, re-loads ----
        int total = 0;
        for (int b0 = 0; b0 < T; b0 += 64) {
            int ll = b0 + lane;
            int dsel = delta[0];
#pragma unroll
            for (int m = 1; m < 9; m++)
                dsel = (ll >= cum[m]) ? delta[m] : dsel;
            float4 q = Qpad[ll + dsel];        // in-bounds: slot<32, cl<=NC
            float dx = q.x - px;
            float dy = q.y - py;
            float s2 = dx * dx + dy * dy;
            int rem = T - b0;
            unsigned long long maskT =
                (rem >= 64) ? ~0ull : ((1ull << rem) - 1ull);
            unsigned long long bal = __ballot(s2 <= S) & maskT;
            int rank = __builtin_amdgcn_mbcnt_hi(
                (unsigned)(bal >> 32),
                __builtin_amdgcn_mbcnt_lo((unsigned)bal, 0));
            int ww = total + rank;
            if ((s2 <= S) && (ll < T) && (ww < MAXNB)) {
                s_id[wsl][ww] = __float_as_int(q.z);
                s_s2[wsl][ww] = s2;
            }
            total += (int)__popcll(bal);
        }
        int stored = min(total, MAXNB);
        int   jj = s_id[wsl][lane];
        float ss = s_s2[wsl][lane];
        bool inb = lane < stored;
        float rh = __builtin_amdgcn_rsqf(S);
        float vN = inb ? (float)jj : -1.0f;
        float vR = inb ? __builtin_amdgcn_sqrtf(ss) * rh : 0.0f;
        size_t base = (size_t)w * MAXNB;
        outN[base + lane] = vN;
        outR[base + lane] = vR;
        if (lane == 0) outC[w] = (float)total;
    }
}

extern "C" void kernel_launch(void* const* d_in, const int* in_sizes, int n_in,
                              void* d_out, int out_size, void* d_ws, size_t ws_size,
                              hipStream_t stream) {
    const float2* pos2 = (const float2*)d_in[0];
    const float*  sup  = (const float*)d_in[1];

    char* p = (char*)d_ws;
    auto alloc = [&](size_t bytes) {
        char* q = p;
        p += (bytes + 255) & ~(size_t)255;
        return q;
    };
    unsigned* params = (unsigned*)alloc(256);
    int*    counts = (int*)alloc((size_t)(NUM_CELLS + 1) * 4);
    float*  bMinX  = (float*)alloc(1024 * 4);
    float*  bMinY  = (float*)alloc(1024 * 4);
    float*  bMaxH  = (float*)alloc(1024 * 4);
    float4* Qraw   = (float4*)alloc((size_t)(NUM_CELLS + 1) * KP * 16);
    float4* Qpad   = (float4*)alloc(((size_t)(NUM_CELLS + 1) * KP + 64) * 16);
    int*    linR   = (int*)alloc((size_t)N_PART * 4);
    int4*   cinfo  = (int4*)alloc((size_t)NUM_CELLS * 4 * 16);

    float* out  = (float*)d_out;
    float* outN = out;                              // N*64 neighbor ids (as f32)
    float* outC = out + (size_t)N_PART * MAXNB;     // N counts
    float* outR = outC + N_PART;                    // N*64 radial

    prep_kernel<<<N_PART / 256, 256, 0, stream>>>(pos2, sup, counts,
                                                  bMinX, bMinY, bMaxH);
    bin_kernel<<<N_PART / 256, 256, 0, stream>>>(pos2, sup, bMinX, bMinY,
                                                 bMaxH, params, counts, Qraw);
    // thread per (cell, slot-class): NUM_CELLS*8 threads
    rank_kernel<<<NUM_CELLS * 8 / 256, 256, 0, stream>>>(counts, Qraw,
                                                         Qpad, linR, cinfo);
    // one wave per particle, ID ORDER: N_PART waves = N_PART/4 blocks
    query_kernel<<<N_PART / 4, 256, 0, stream>>>(linR, cinfo, Qpad,
                                                 outN, outC, outR);
}